// Round 4
// baseline (94.073 us; speedup 1.0000x reference)
//
#include <hip/hip_runtime.h>
#include <hip/hip_bf16.h>

typedef __bf16 bf16;
typedef __bf16 bf16x4 __attribute__((ext_vector_type(4)));
typedef __bf16 bf16x8 __attribute__((ext_vector_type(8)));
typedef float f32x4 __attribute__((ext_vector_type(4)));

// async global->LDS, 16B per lane. LDS dest must be wave-uniform (base+lane*16 is HW).
__device__ __forceinline__ void gload16(const void* g, void* l) {
  __builtin_amdgcn_global_load_lds(
      (const __attribute__((address_space(1))) unsigned int*)g,
      (__attribute__((address_space(3))) unsigned int*)l, 16, 0, 0);
}

// Layouts (bf16, BK=64 chunks, 128B rows, swizzle: elem col ^= (row&7)<<3):
//  Pk:    [bh][kb16][row c(256)][64]   (k-dim = l)  row-XOR uses c&7
//  Vt:    [bh][kb4][row l(1024)][64]   (k-dim = c)  row-XOR uses l&7
//  Pattn: [bh][kb4][row c(256)][64]    (k-dim = d)  row-XOR uses c&7

// ---------------- Kernel A: k-projection (x<256) + v-projection (x>=256), one launch
__global__ __launch_bounds__(256) void proj_kv(
    const float* __restrict__ kin, const float* __restrict__ vin,
    const float* __restrict__ wk, const float* __restrict__ bk,
    const float* __restrict__ wv, const float* __restrict__ bv,
    bf16* __restrict__ Pk, bf16* __restrict__ Vt) {
  int b = blockIdx.y;
  int x = blockIdx.x;
  int t = threadIdx.x;
  __shared__ float ch[4224];   // k-path: 4096; v-path: 32*2*66 = 4224
  if (x < 256) {
    // ---- k projection, group g = x
    int g = x;
    {
      const float4* src = reinterpret_cast<const float4*>(kin + ((size_t)b*256 + g)*4096);
      float4* dst4 = reinterpret_cast<float4*>(ch);
#pragma unroll
      for (int i = 0; i < 4; i++) dst4[t + i*256] = src[t + i*256];
    }
    int j = t >> 5, i = t & 31;
    float4 wvv = reinterpret_cast<const float4*>(wk)[g*8 + j];
    float bj = bk[g*8 + j];
    __syncthreads();
    int h = g >> 5;
    int c = (g & 31)*8 + j;
    int bh = b*8 + h;
#pragma unroll
    for (int p = 0; p < 4; p++) {
      int l0 = p*256 + i*8;
      int m = l0 >> 5, kb = l0 >> 6, kp0 = l0 & 63, n0 = l0 & 31;
      float rr0[16], rr1[16];
      const float4* R0 = reinterpret_cast<const float4*>(ch + (2*m)*64 + 2*n0);
      const float4* R1 = reinterpret_cast<const float4*>(ch + (2*m+1)*64 + 2*n0);
#pragma unroll
      for (int u = 0; u < 4; u++) {
        *reinterpret_cast<float4*>(rr0 + u*4) = R0[u];
        *reinterpret_cast<float4*>(rr1 + u*4) = R1[u];
      }
      bf16x8 o;
#pragma unroll
      for (int u = 0; u < 8; u++)
        o[u] = (bf16)(bj + wvv.x*rr0[2*u] + wvv.y*rr0[2*u+1] + wvv.z*rr1[2*u] + wvv.w*rr1[2*u+1]);
      size_t off = (((size_t)bh*16 + kb)*256 + c)*64 + (kp0 ^ (j << 3));
      *reinterpret_cast<bf16x8*>(Pk + off) = o;
    }
  } else {
    // ---- v projection into swizzled chunk-transposed Vt
    int r = x - 256;
    int m = r & 31, h = r >> 5;
    {
      int seg = t >> 2, part = t & 3;
      int gl = seg >> 1, ky = seg & 1;
      const float* src = vin + (((size_t)b*256 + h*32 + gl)*64 + (2*m + ky))*64;
      float* drow = ch + (gl*2 + ky)*66;
#pragma unroll
      for (int i = 0; i < 4; i++) {
        float4 v = reinterpret_cast<const float4*>(src)[part + i*4];
        int x0 = (part + i*4)*4;
        drow[x0]=v.x; drow[x0+1]=v.y; drow[x0+2]=v.z; drow[x0+3]=v.w;
      }
    }
    int cgrp = t & 31, lgr = t >> 5;
    int c0 = cgrp*8;
    float4 wv8[8]; float bb8[8];
#pragma unroll
    for (int u = 0; u < 8; u++) {
      wv8[u] = reinterpret_cast<const float4*>(wv)[h*256 + c0 + u];
      bb8[u] = bv[h*256 + c0 + u];
    }
    __syncthreads();
    const float* r0 = ch + (cgrp*2 + 0)*66;
    const float* r1 = ch + (cgrp*2 + 1)*66;
    int bh = b*8 + h;
    bf16* base = Vt + ((size_t)bh*4 + (c0 >> 6))*1024*64;
    int colx = (c0 & 63) ^ (lgr << 3);
#pragma unroll
    for (int p = 0; p < 4; p++) {
      int n = p*8 + lgr;
      int l = m*32 + n;
      float c00 = r0[2*n], c01 = r0[2*n+1], c10 = r1[2*n], c11 = r1[2*n+1];
      bf16x8 o;
#pragma unroll
      for (int u = 0; u < 8; u++)
        o[u] = (bf16)(bb8[u] + wv8[u].x*c00 + wv8[u].y*c01 + wv8[u].z*c10 + wv8[u].w*c11);
      *reinterpret_cast<bf16x8*>(base + (size_t)l*64 + colx) = o;
    }
  }
}

// ---------------- Kernel B: fused Q-proj + S = Q K^T + softmax -> Pattn.
// 512 blocks, 4 waves; 32 c-rows/block. Q held in registers (16 bf16x8 granules).
__global__ __launch_bounds__(256, 2) void attn_fused(
    const float* __restrict__ qraw, const float* __restrict__ wq,
    const float* __restrict__ bq, const bf16* __restrict__ Pk,
    bf16* __restrict__ Pattn) {
  int raw = blockIdx.x;
  int loc = raw >> 3;
  int bh = (raw & 7)*8 + (loc >> 3);   // 8 c-strips of one bh share an XCD
  int tb = loc & 7;
  int c0 = tb*32;
  int b = bh >> 3, h = bh & 7;
  int t = threadIdx.x, wave = t >> 6, lane = t & 63, lg = lane >> 4, lr = lane & 15;
  int cl = lane & 7, cg = lane >> 3;   // c_local (=j), col-group
  __shared__ bf16 Kl[256*64];     // 32 KB, one K chunk
  __shared__ bf16 Ql[32*64];      // 4 KB, one Q chunk
  __shared__ float red_s[4][32];
  // ---- Q projection prologue: conv of raw q channel g into 16 bf16x8 granules
  int g = h*32 + tb*4 + wave;          // this wave's conv group / input channel
  const float* qch = qraw + ((size_t)b*256 + g)*4096;
  float4 wvq = reinterpret_cast<const float4*>(wq)[g*8 + cl];
  float bj = bq[g*8 + cl];
  bf16x8 qreg[16];
  int x0 = (cg & 3)*16;
  int yb = (cg >> 2)*2;
#pragma unroll 4
  for (int kb = 0; kb < 16; kb++) {
    int y0 = kb*4 + yb;
    const float4* R0 = reinterpret_cast<const float4*>(qch + y0*64 + x0);
    const float4* R1 = reinterpret_cast<const float4*>(qch + (y0+1)*64 + x0);
    float f0[16], f1[16];
#pragma unroll
    for (int u = 0; u < 4; u++) {
      *reinterpret_cast<float4*>(f0 + u*4) = R0[u];
      *reinterpret_cast<float4*>(f1 + u*4) = R1[u];
    }
    bf16x8 o;
#pragma unroll
    for (int u = 0; u < 8; u++)
      o[u] = (bf16)(bj + wvq.x*f0[2*u] + wvq.y*f0[2*u+1] + wvq.z*f1[2*u] + wvq.w*f1[2*u+1]);
    qreg[kb] = o;
  }
  // ---- main loop over 16 K-chunks
  const char* Kbase = (const char*)Pk + (size_t)bh*16*32768;
  bf16* qlw = Ql + (wave*8 + cl)*64 + ((cg*8) ^ (cl << 3));
  f32x4 acc[2][4];
#pragma unroll
  for (int i = 0; i < 2; i++)
#pragma unroll
    for (int j = 0; j < 4; j++) { f32x4 z = {0.f,0.f,0.f,0.f}; acc[i][j] = z; }
  for (int kb = 0; kb < 16; kb++) {
    __syncthreads();                       // prior chunk's LDS reads done
    *reinterpret_cast<bf16x8*>(qlw) = qreg[kb];
    {
      const char* kc = Kbase + (size_t)kb*32768 + wave*8192 + lane*16;
      char* klp = (char*)Kl + wave*8192;
#pragma unroll
      for (int i = 0; i < 8; i++) gload16(kc + i*1024, klp + i*1024);
    }
    __syncthreads();                       // barrier drains vmcnt+lgkm -> LDS filled
#pragma unroll
    for (int ks = 0; ks < 2; ks++) {
      int colx = (ks*32 + lg*8) ^ ((lr & 7) << 3);
      bf16x8 a0 = *reinterpret_cast<const bf16x8*>(Ql + lr*64 + colx);
      bf16x8 a1 = *reinterpret_cast<const bf16x8*>(Ql + (16 + lr)*64 + colx);
#pragma unroll
      for (int ni = 0; ni < 4; ni++) {
        bf16x8 bv2 = *reinterpret_cast<const bf16x8*>(Kl + (wave*64 + ni*16 + lr)*64 + colx);
        acc[0][ni] = __builtin_amdgcn_mfma_f32_16x16x32_bf16(a0, bv2, acc[0][ni], 0, 0, 0);
        acc[1][ni] = __builtin_amdgcn_mfma_f32_16x16x32_bf16(a1, bv2, acc[1][ni], 0, 0, 0);
      }
    }
  }
  // softmax over d (wave holds 64 d; combine 4 waves via red_s)
  const float scale = 0.03125f;
  float sums[2][4];
#pragma unroll
  for (int mi = 0; mi < 2; mi++)
#pragma unroll
    for (int r = 0; r < 4; r++) {
      float mx = fmaxf(fmaxf(acc[mi][0][r], acc[mi][1][r]), fmaxf(acc[mi][2][r], acc[mi][3][r]));
#pragma unroll
      for (int off = 1; off < 16; off <<= 1) mx = fmaxf(mx, __shfl_xor(mx, off, 64));
      red_s[wave][mi*16 + lg*4 + r] = mx;
    }
  __syncthreads();
#pragma unroll
  for (int mi = 0; mi < 2; mi++)
#pragma unroll
    for (int r = 0; r < 4; r++) {
      int clr = mi*16 + lg*4 + r;
      float mx = fmaxf(fmaxf(red_s[0][clr], red_s[1][clr]), fmaxf(red_s[2][clr], red_s[3][clr]));
      float s = 0.f;
#pragma unroll
      for (int ni = 0; ni < 4; ni++) {
        float p = __expf(scale*(acc[mi][ni][r] - mx));
        acc[mi][ni][r] = p; s += p;
      }
#pragma unroll
      for (int off = 1; off < 16; off <<= 1) s += __shfl_xor(s, off, 64);
      sums[mi][r] = s;
    }
  __syncthreads();
#pragma unroll
  for (int mi = 0; mi < 2; mi++)
#pragma unroll
    for (int r = 0; r < 4; r++) red_s[wave][mi*16 + lg*4 + r] = sums[mi][r];
  __syncthreads();
  // normalize + stage P strip into LDS (reuse Kl) in swizzled chunk layout
  bf16* Pst = Kl;
#pragma unroll
  for (int mi = 0; mi < 2; mi++)
#pragma unroll
    for (int r = 0; r < 4; r++) {
      int clr = mi*16 + lg*4 + r;
      float iv = 1.f/(red_s[0][clr] + red_s[1][clr] + red_s[2][clr] + red_s[3][clr]);
#pragma unroll
      for (int ni = 0; ni < 4; ni++) {
        int dl = ni*16 + lr;
        Pst[wave*2048 + clr*64 + (dl ^ ((clr & 7) << 3))] = (bf16)(acc[mi][ni][r]*iv);
      }
    }
  __syncthreads();
  // coalesced copy-out: 4 pieces of 4KB
  const uint4* ls = reinterpret_cast<const uint4*>(Kl);
#pragma unroll
  for (int i = 0; i < 4; i++) {
    uint4* gp = reinterpret_cast<uint4*>((char*)Pattn + (((size_t)bh*4 + i)*256 + c0)*128);
    gp[t] = ls[i*256 + t];
  }
}

// ---------------- Kernel C: O = Pattn * V (K=256), fused deconv + bias + residual
__global__ __launch_bounds__(256, 4) void pv_deconv(const bf16* __restrict__ Pattn,
    const bf16* __restrict__ Vt, const float* __restrict__ qin,
    const float* __restrict__ wo, const float* __restrict__ bo,
    const float* __restrict__ gamma, float* __restrict__ outp) {
  int raw = blockIdx.x;
  int idx = raw >> 3;
  int pair = (raw & 7)*32 + (idx >> 2);   // (mb,bh); 4 tb-blocks share V chunk + XCD
  int tb = idx & 3;
  int mb = pair & 3, bh = pair >> 2;
  int h = bh & 7, b = bh >> 3;
  int t = threadIdx.x, wave = t >> 6, lane = t & 63, lg = lane >> 4, lr = lane & 15;
  __shared__ __attribute__((aligned(16))) char smem[40960];
  bf16* Pl   = reinterpret_cast<bf16*>(smem);            // 8192 B
  bf16* Vl   = reinterpret_cast<bf16*>(smem + 8192);     // 32768 B
  bf16* OlT  = reinterpret_cast<bf16*>(smem);            // 256*66*2 = 33792 B (post-loop)
  float* wo_s = reinterpret_cast<float*>(smem + 36864);  // 1024 B (post-loop)
  float* bo_s = reinterpret_cast<float*>(smem + 37888);  // 32 B
  const char* Pbase = (const char*)Pattn + ((size_t)bh*4*256 + tb*64)*128;
  const char* Vbase = (const char*)Vt + ((size_t)bh*4*1024 + mb*256)*128;
  f32x4 acc[4][4];
#pragma unroll
  for (int i = 0; i < 4; i++)
#pragma unroll
    for (int j = 0; j < 4; j++) { f32x4 z = {0.f,0.f,0.f,0.f}; acc[i][j] = z; }
  for (int kb = 0; kb < 4; kb++) {
    __syncthreads();
    {
      const char* pc = Pbase + (size_t)kb*32768 + wave*2048 + lane*16;
      char* pl = (char*)Pl + wave*2048;
#pragma unroll
      for (int i = 0; i < 2; i++) gload16(pc + i*1024, pl + i*1024);
      const char* vc = Vbase + (size_t)kb*131072 + wave*8192 + lane*16;
      char* vl = (char*)Vl + wave*8192;
#pragma unroll
      for (int i = 0; i < 8; i++) gload16(vc + i*1024, vl + i*1024);
    }
    __syncthreads();
#pragma unroll
    for (int ks = 0; ks < 2; ks++) {
      int colx = (ks*32 + lg*8) ^ ((lr & 7) << 3);
      bf16x8 a[4];
#pragma unroll
      for (int mi = 0; mi < 4; mi++)
        a[mi] = *reinterpret_cast<const bf16x8*>(Pl + (mi*16 + lr)*64 + colx);
#pragma unroll
      for (int ni = 0; ni < 4; ni++) {
        bf16x8 bv2 = *reinterpret_cast<const bf16x8*>(Vl + (wave*64 + ni*16 + lr)*64 + colx);
#pragma unroll
        for (int mi = 0; mi < 4; mi++)
          acc[mi][ni] = __builtin_amdgcn_mfma_f32_16x16x32_bf16(a[mi], bv2, acc[mi][ni], 0, 0, 0);
      }
    }
  }
  __syncthreads();   // all MFMA LDS reads done before OlT/wo_s overwrite
#pragma unroll
  for (int mi = 0; mi < 4; mi++)
#pragma unroll
    for (int ni = 0; ni < 4; ni++) {
      int l = wave*64 + ni*16 + lr;
      int cb = mi*16 + lg*4;
      bf16x4 p;
      p[0] = (bf16)acc[mi][ni][0]; p[1] = (bf16)acc[mi][ni][1];
      p[2] = (bf16)acc[mi][ni][2]; p[3] = (bf16)acc[mi][ni][3];
      *reinterpret_cast<bf16x4*>(OlT + l*66 + cb) = p;
    }
  wo_s[t] = wo[((size_t)(h*32 + tb*8 + (t>>5)))*32 + (t & 31)];
  if (t < 8) bo_s[t] = bo[h*32 + tb*8 + t];
  __syncthreads();
  // epilogue: deconv 2x2 stride 2 + bias + residual; fully coalesced float4 I/O
  int xq = t & 15, b5 = (t >> 4) & 1, ct = t >> 5;
  float2 wp[8];
#pragma unroll
  for (int j = 0; j < 8; j++)
    wp[j] = *reinterpret_cast<const float2*>(wo_s + ct*32 + j*4 + (1 - b5)*2);
  float bias = bo_s[ct];
  float gm = gamma[0];
  int co = h*32 + tb*8 + ct;
#pragma unroll
  for (int it = 0; it < 8; it++) {
    int y = it*2 + b5;
    int ll0 = it*32 + xq*2;
    bf16x4 o00 = *reinterpret_cast<const bf16x4*>(OlT + ll0*66 + ct*8);
    bf16x4 o01 = *reinterpret_cast<const bf16x4*>(OlT + ll0*66 + ct*8 + 4);
    bf16x4 o10 = *reinterpret_cast<const bf16x4*>(OlT + (ll0+1)*66 + ct*8);
    bf16x4 o11 = *reinterpret_cast<const bf16x4*>(OlT + (ll0+1)*66 + ct*8 + 4);
    float v0 = bias, v1 = bias, v2 = bias, v3 = bias;
#pragma unroll
    for (int j = 0; j < 4; j++) {
      float f0 = (float)o00[j], f1 = (float)o01[j];
      v0 += f0*wp[j].y;   v1 += f0*wp[j].x;
      v0 += f1*wp[4+j].y; v1 += f1*wp[4+j].x;
      float g0 = (float)o10[j], g1 = (float)o11[j];
      v2 += g0*wp[j].y;   v3 += g0*wp[j].x;
      v2 += g1*wp[4+j].y; v3 += g1*wp[4+j].x;
    }
    size_t oi = (((size_t)b*256 + co)*64 + (mb*16 + y))*64 + xq*4;
    float4 qv = *reinterpret_cast<const float4*>(qin + oi);
    float4 ov;
    ov.x = qv.x + gm*v0; ov.y = qv.y + gm*v1;
    ov.z = qv.z + gm*v2; ov.w = qv.w + gm*v3;
    *reinterpret_cast<float4*>(outp + oi) = ov;
  }
}

extern "C" void kernel_launch(void* const* d_in, const int* in_sizes, int n_in,
                              void* d_out, int out_size, void* d_ws, size_t ws_size,
                              hipStream_t stream) {
  const float* q  = (const float*)d_in[0];
  const float* k  = (const float*)d_in[1];
  const float* v  = (const float*)d_in[2];
  const float* wq = (const float*)d_in[3];
  const float* bq = (const float*)d_in[4];
  const float* wk = (const float*)d_in[5];
  const float* bk = (const float*)d_in[6];
  const float* wv = (const float*)d_in[7];
  const float* bv = (const float*)d_in[8];
  const float* wo = (const float*)d_in[9];
  const float* bo = (const float*)d_in[10];
  const float* gamma = (const float*)d_in[11];
  float* out = (float*)d_out;

  char* ws = (char*)d_ws;
  bf16* Pk    = (bf16*)(ws);              //  33,554,432 B
  bf16* Vt    = (bf16*)(ws + 33554432);   //  33,554,432 B
  bf16* Pattn = (bf16*)(ws + 67108864);   //   8,388,608 B

  proj_kv  <<<dim3(512, 8), 256, 0, stream>>>(k, v, wk, bk, wv, bv, Pk, Vt);
  attn_fused<<<dim3(512), 256, 0, stream>>>(q, wq, bq, Pk, Pattn);
  pv_deconv<<<dim3(1024), 256, 0, stream>>>(Pattn, Vt, q, wo, bo, gamma, out);
}

// Round 5
// 85.274 us; speedup vs baseline: 1.1032x; 1.1032x over previous
//
#include <hip/hip_runtime.h>
#include <hip/hip_bf16.h>

typedef __bf16 bf16;
typedef __bf16 bf16x4 __attribute__((ext_vector_type(4)));
typedef __bf16 bf16x8 __attribute__((ext_vector_type(8)));
typedef float f32x4 __attribute__((ext_vector_type(4)));

// async global->LDS, 16B per lane. LDS dest must be wave-uniform (base+lane*16 is HW).
__device__ __forceinline__ void gload16(const void* g, void* l) {
  __builtin_amdgcn_global_load_lds(
      (const __attribute__((address_space(1))) unsigned int*)g,
      (__attribute__((address_space(3))) unsigned int*)l, 16, 0, 0);
}

// Layouts (bf16, BK=64 chunks, 128B rows, swizzle: elem col ^= (row&7)<<3):
//  Pk:    [bh][kb16][row c(256)][64]   (k-dim = l)  row-XOR uses c&7
//  Vt:    [bh][kb4][row l(1024)][64]   (k-dim = c)  row-XOR uses l&7
//  Pattn: [bh][kb4][row c(256)][64]    (k-dim = d)  row-XOR uses c&7

// ---------------- Kernel A: k-projection (x<256) + v-projection (x>=256), one launch
__global__ __launch_bounds__(256) void proj_kv(
    const float* __restrict__ kin, const float* __restrict__ vin,
    const float* __restrict__ wk, const float* __restrict__ bk,
    const float* __restrict__ wv, const float* __restrict__ bv,
    bf16* __restrict__ Pk, bf16* __restrict__ Vt) {
  int b = blockIdx.y;
  int x = blockIdx.x;
  int t = threadIdx.x;
  __shared__ float ch[4224];   // k-path: 4096; v-path: 32*2*66 = 4224
  if (x < 256) {
    // ---- k projection, group g = x
    int g = x;
    {
      const float4* src = reinterpret_cast<const float4*>(kin + ((size_t)b*256 + g)*4096);
      float4* dst4 = reinterpret_cast<float4*>(ch);
#pragma unroll
      for (int i = 0; i < 4; i++) dst4[t + i*256] = src[t + i*256];
    }
    int j = t >> 5, i = t & 31;
    float4 wvv = reinterpret_cast<const float4*>(wk)[g*8 + j];
    float bj = bk[g*8 + j];
    __syncthreads();
    int h = g >> 5;
    int c = (g & 31)*8 + j;
    int bh = b*8 + h;
#pragma unroll
    for (int p = 0; p < 4; p++) {
      int l0 = p*256 + i*8;
      int m = l0 >> 5, kb = l0 >> 6, kp0 = l0 & 63, n0 = l0 & 31;
      float rr0[16], rr1[16];
      const float4* R0 = reinterpret_cast<const float4*>(ch + (2*m)*64 + 2*n0);
      const float4* R1 = reinterpret_cast<const float4*>(ch + (2*m+1)*64 + 2*n0);
#pragma unroll
      for (int u = 0; u < 4; u++) {
        *reinterpret_cast<float4*>(rr0 + u*4) = R0[u];
        *reinterpret_cast<float4*>(rr1 + u*4) = R1[u];
      }
      bf16x8 o;
#pragma unroll
      for (int u = 0; u < 8; u++)
        o[u] = (bf16)(bj + wvv.x*rr0[2*u] + wvv.y*rr0[2*u+1] + wvv.z*rr1[2*u] + wvv.w*rr1[2*u+1]);
      size_t off = (((size_t)bh*16 + kb)*256 + c)*64 + (kp0 ^ (j << 3));
      *reinterpret_cast<bf16x8*>(Pk + off) = o;
    }
  } else {
    // ---- v projection into swizzled chunk-transposed Vt
    int r = x - 256;
    int m = r & 31, h = r >> 5;
    {
      int seg = t >> 2, part = t & 3;
      int gl = seg >> 1, ky = seg & 1;
      const float* src = vin + (((size_t)b*256 + h*32 + gl)*64 + (2*m + ky))*64;
      float* drow = ch + (gl*2 + ky)*66;
#pragma unroll
      for (int i = 0; i < 4; i++) {
        float4 v = reinterpret_cast<const float4*>(src)[part + i*4];
        int x0 = (part + i*4)*4;
        drow[x0]=v.x; drow[x0+1]=v.y; drow[x0+2]=v.z; drow[x0+3]=v.w;
      }
    }
    int cgrp = t & 31, lgr = t >> 5;
    int c0 = cgrp*8;
    float4 wv8[8]; float bb8[8];
#pragma unroll
    for (int u = 0; u < 8; u++) {
      wv8[u] = reinterpret_cast<const float4*>(wv)[h*256 + c0 + u];
      bb8[u] = bv[h*256 + c0 + u];
    }
    __syncthreads();
    const float* r0 = ch + (cgrp*2 + 0)*66;
    const float* r1 = ch + (cgrp*2 + 1)*66;
    int bh = b*8 + h;
    bf16* base = Vt + ((size_t)bh*4 + (c0 >> 6))*1024*64;
    int colx = (c0 & 63) ^ (lgr << 3);
#pragma unroll
    for (int p = 0; p < 4; p++) {
      int n = p*8 + lgr;
      int l = m*32 + n;
      float c00 = r0[2*n], c01 = r0[2*n+1], c10 = r1[2*n], c11 = r1[2*n+1];
      bf16x8 o;
#pragma unroll
      for (int u = 0; u < 8; u++)
        o[u] = (bf16)(bb8[u] + wv8[u].x*c00 + wv8[u].y*c01 + wv8[u].z*c10 + wv8[u].w*c11);
      *reinterpret_cast<bf16x8*>(base + (size_t)l*64 + colx) = o;
    }
  }
}

// ---------------- Kernel B: fused Q-proj + S = Q K^T + softmax -> Pattn.
// 512 blocks, 4 waves; 32 c-rows/block. Q held in registers (16 bf16x8 granules,
// ALL indexing compile-time static: both kb loops fully unrolled -> no scratch).
__global__ __launch_bounds__(256, 2) void attn_fused(
    const float* __restrict__ qraw, const float* __restrict__ wq,
    const float* __restrict__ bq, const bf16* __restrict__ Pk,
    bf16* __restrict__ Pattn) {
  int raw = blockIdx.x;
  int loc = raw >> 3;
  int bh = (raw & 7)*8 + (loc >> 3);   // 8 c-strips of one bh share an XCD
  int tb = loc & 7;
  int c0 = tb*32;
  int b = bh >> 3, h = bh & 7;
  int t = threadIdx.x, wave = t >> 6, lane = t & 63, lg = lane >> 4, lr = lane & 15;
  int cl = lane & 7, cg = lane >> 3;   // c_local (=j), col-group
  __shared__ bf16 Kl[256*64];     // 32 KB, one K chunk
  __shared__ bf16 Ql[32*64];      // 4 KB, one Q chunk
  __shared__ float red_s[4][32];
  // ---- Q projection prologue: conv of raw q channel g into 16 bf16x8 granules
  int g = h*32 + tb*4 + wave;          // this wave's conv group / input channel
  const float* qch = qraw + ((size_t)b*256 + g)*4096;
  float4 wvq = reinterpret_cast<const float4*>(wq)[g*8 + cl];
  float bj = bq[g*8 + cl];
  bf16x8 qreg[16];
  int x0 = (cg & 3)*16;
  int yb = (cg >> 2)*2;
#pragma unroll
  for (int kb = 0; kb < 16; kb++) {
    int y0 = kb*4 + yb;
    const float4* R0 = reinterpret_cast<const float4*>(qch + y0*64 + x0);
    const float4* R1 = reinterpret_cast<const float4*>(qch + (y0+1)*64 + x0);
    float f0[16], f1[16];
#pragma unroll
    for (int u = 0; u < 4; u++) {
      *reinterpret_cast<float4*>(f0 + u*4) = R0[u];
      *reinterpret_cast<float4*>(f1 + u*4) = R1[u];
    }
    bf16x8 o;
#pragma unroll
    for (int u = 0; u < 8; u++)
      o[u] = (bf16)(bj + wvq.x*f0[2*u] + wvq.y*f0[2*u+1] + wvq.z*f1[2*u] + wvq.w*f1[2*u+1]);
    qreg[kb] = o;
  }
  // ---- main loop over 16 K-chunks (fully unrolled: qreg[kb] static)
  const char* Kbase = (const char*)Pk + (size_t)bh*16*32768;
  bf16* qlw = Ql + (wave*8 + cl)*64 + ((cg*8) ^ (cl << 3));
  f32x4 acc[2][4];
#pragma unroll
  for (int i = 0; i < 2; i++)
#pragma unroll
    for (int j = 0; j < 4; j++) { f32x4 z = {0.f,0.f,0.f,0.f}; acc[i][j] = z; }
#pragma unroll
  for (int kb = 0; kb < 16; kb++) {
    __syncthreads();                       // prior chunk's LDS reads done
    *reinterpret_cast<bf16x8*>(qlw) = qreg[kb];
    {
      const char* kc = Kbase + (size_t)kb*32768 + wave*8192 + lane*16;
      char* klp = (char*)Kl + wave*8192;
#pragma unroll
      for (int i = 0; i < 8; i++) gload16(kc + i*1024, klp + i*1024);
    }
    __syncthreads();                       // barrier drains vmcnt+lgkm -> LDS filled
#pragma unroll
    for (int ks = 0; ks < 2; ks++) {
      int colx = (ks*32 + lg*8) ^ ((lr & 7) << 3);
      bf16x8 a0 = *reinterpret_cast<const bf16x8*>(Ql + lr*64 + colx);
      bf16x8 a1 = *reinterpret_cast<const bf16x8*>(Ql + (16 + lr)*64 + colx);
#pragma unroll
      for (int ni = 0; ni < 4; ni++) {
        bf16x8 bv2 = *reinterpret_cast<const bf16x8*>(Kl + (wave*64 + ni*16 + lr)*64 + colx);
        acc[0][ni] = __builtin_amdgcn_mfma_f32_16x16x32_bf16(a0, bv2, acc[0][ni], 0, 0, 0);
        acc[1][ni] = __builtin_amdgcn_mfma_f32_16x16x32_bf16(a1, bv2, acc[1][ni], 0, 0, 0);
      }
    }
  }
  // softmax over d (wave holds 64 d; combine 4 waves via red_s)
  const float scale = 0.03125f;
  float sums[2][4];
#pragma unroll
  for (int mi = 0; mi < 2; mi++)
#pragma unroll
    for (int r = 0; r < 4; r++) {
      float mx = fmaxf(fmaxf(acc[mi][0][r], acc[mi][1][r]), fmaxf(acc[mi][2][r], acc[mi][3][r]));
#pragma unroll
      for (int off = 1; off < 16; off <<= 1) mx = fmaxf(mx, __shfl_xor(mx, off, 64));
      red_s[wave][mi*16 + lg*4 + r] = mx;
    }
  __syncthreads();
#pragma unroll
  for (int mi = 0; mi < 2; mi++)
#pragma unroll
    for (int r = 0; r < 4; r++) {
      int clr = mi*16 + lg*4 + r;
      float mx = fmaxf(fmaxf(red_s[0][clr], red_s[1][clr]), fmaxf(red_s[2][clr], red_s[3][clr]));
      float s = 0.f;
#pragma unroll
      for (int ni = 0; ni < 4; ni++) {
        float p = __expf(scale*(acc[mi][ni][r] - mx));
        acc[mi][ni][r] = p; s += p;
      }
#pragma unroll
      for (int off = 1; off < 16; off <<= 1) s += __shfl_xor(s, off, 64);
      sums[mi][r] = s;
    }
  __syncthreads();
#pragma unroll
  for (int mi = 0; mi < 2; mi++)
#pragma unroll
    for (int r = 0; r < 4; r++) red_s[wave][mi*16 + lg*4 + r] = sums[mi][r];
  __syncthreads();
  // normalize + stage P strip into LDS (reuse Kl) in swizzled chunk layout
  bf16* Pst = Kl;
#pragma unroll
  for (int mi = 0; mi < 2; mi++)
#pragma unroll
    for (int r = 0; r < 4; r++) {
      int clr = mi*16 + lg*4 + r;
      float iv = 1.f/(red_s[0][clr] + red_s[1][clr] + red_s[2][clr] + red_s[3][clr]);
#pragma unroll
      for (int ni = 0; ni < 4; ni++) {
        int dl = ni*16 + lr;
        Pst[wave*2048 + clr*64 + (dl ^ ((clr & 7) << 3))] = (bf16)(acc[mi][ni][r]*iv);
      }
    }
  __syncthreads();
  // coalesced copy-out: 4 pieces of 4KB
  const uint4* ls = reinterpret_cast<const uint4*>(Kl);
#pragma unroll
  for (int i = 0; i < 4; i++) {
    uint4* gp = reinterpret_cast<uint4*>((char*)Pattn + (((size_t)bh*4 + i)*256 + c0)*128);
    gp[t] = ls[i*256 + t];
  }
}

// ---------------- Kernel C: O = Pattn * V (K=256), fused deconv + bias + residual
__global__ __launch_bounds__(256, 4) void pv_deconv(const bf16* __restrict__ Pattn,
    const bf16* __restrict__ Vt, const float* __restrict__ qin,
    const float* __restrict__ wo, const float* __restrict__ bo,
    const float* __restrict__ gamma, float* __restrict__ outp) {
  int raw = blockIdx.x;
  int idx = raw >> 3;
  int pair = (raw & 7)*32 + (idx >> 2);   // (mb,bh); 4 tb-blocks share V chunk + XCD
  int tb = idx & 3;
  int mb = pair & 3, bh = pair >> 2;
  int h = bh & 7, b = bh >> 3;
  int t = threadIdx.x, wave = t >> 6, lane = t & 63, lg = lane >> 4, lr = lane & 15;
  __shared__ __attribute__((aligned(16))) char smem[40960];
  bf16* Pl   = reinterpret_cast<bf16*>(smem);            // 8192 B
  bf16* Vl   = reinterpret_cast<bf16*>(smem + 8192);     // 32768 B
  bf16* OlT  = reinterpret_cast<bf16*>(smem);            // 256*66*2 = 33792 B (post-loop)
  float* wo_s = reinterpret_cast<float*>(smem + 36864);  // 1024 B (post-loop)
  float* bo_s = reinterpret_cast<float*>(smem + 37888);  // 32 B
  const char* Pbase = (const char*)Pattn + ((size_t)bh*4*256 + tb*64)*128;
  const char* Vbase = (const char*)Vt + ((size_t)bh*4*1024 + mb*256)*128;
  f32x4 acc[4][4];
#pragma unroll
  for (int i = 0; i < 4; i++)
#pragma unroll
    for (int j = 0; j < 4; j++) { f32x4 z = {0.f,0.f,0.f,0.f}; acc[i][j] = z; }
  for (int kb = 0; kb < 4; kb++) {
    __syncthreads();
    {
      const char* pc = Pbase + (size_t)kb*32768 + wave*2048 + lane*16;
      char* pl = (char*)Pl + wave*2048;
#pragma unroll
      for (int i = 0; i < 2; i++) gload16(pc + i*1024, pl + i*1024);
      const char* vc = Vbase + (size_t)kb*131072 + wave*8192 + lane*16;
      char* vl = (char*)Vl + wave*8192;
#pragma unroll
      for (int i = 0; i < 8; i++) gload16(vc + i*1024, vl + i*1024);
    }
    __syncthreads();
#pragma unroll
    for (int ks = 0; ks < 2; ks++) {
      int colx = (ks*32 + lg*8) ^ ((lr & 7) << 3);
      bf16x8 a[4];
#pragma unroll
      for (int mi = 0; mi < 4; mi++)
        a[mi] = *reinterpret_cast<const bf16x8*>(Pl + (mi*16 + lr)*64 + colx);
#pragma unroll
      for (int ni = 0; ni < 4; ni++) {
        bf16x8 bv2 = *reinterpret_cast<const bf16x8*>(Vl + (wave*64 + ni*16 + lr)*64 + colx);
#pragma unroll
        for (int mi = 0; mi < 4; mi++)
          acc[mi][ni] = __builtin_amdgcn_mfma_f32_16x16x32_bf16(a[mi], bv2, acc[mi][ni], 0, 0, 0);
      }
    }
  }
  __syncthreads();   // all MFMA LDS reads done before OlT/wo_s overwrite
#pragma unroll
  for (int mi = 0; mi < 4; mi++)
#pragma unroll
    for (int ni = 0; ni < 4; ni++) {
      int l = wave*64 + ni*16 + lr;
      int cb = mi*16 + lg*4;
      bf16x4 p;
      p[0] = (bf16)acc[mi][ni][0]; p[1] = (bf16)acc[mi][ni][1];
      p[2] = (bf16)acc[mi][ni][2]; p[3] = (bf16)acc[mi][ni][3];
      *reinterpret_cast<bf16x4*>(OlT + l*66 + cb) = p;
    }
  wo_s[t] = wo[((size_t)(h*32 + tb*8 + (t>>5)))*32 + (t & 31)];
  if (t < 8) bo_s[t] = bo[h*32 + tb*8 + t];
  __syncthreads();
  // epilogue: deconv 2x2 stride 2 + bias + residual; fully coalesced float4 I/O
  int xq = t & 15, b5 = (t >> 4) & 1, ct = t >> 5;
  float2 wp[8];
#pragma unroll
  for (int j = 0; j < 8; j++)
    wp[j] = *reinterpret_cast<const float2*>(wo_s + ct*32 + j*4 + (1 - b5)*2);
  float bias = bo_s[ct];
  float gm = gamma[0];
  int co = h*32 + tb*8 + ct;
#pragma unroll
  for (int it = 0; it < 8; it++) {
    int y = it*2 + b5;
    int ll0 = it*32 + xq*2;
    bf16x4 o00 = *reinterpret_cast<const bf16x4*>(OlT + ll0*66 + ct*8);
    bf16x4 o01 = *reinterpret_cast<const bf16x4*>(OlT + ll0*66 + ct*8 + 4);
    bf16x4 o10 = *reinterpret_cast<const bf16x4*>(OlT + (ll0+1)*66 + ct*8);
    bf16x4 o11 = *reinterpret_cast<const bf16x4*>(OlT + (ll0+1)*66 + ct*8 + 4);
    float v0 = bias, v1 = bias, v2 = bias, v3 = bias;
#pragma unroll
    for (int j = 0; j < 4; j++) {
      float f0 = (float)o00[j], f1 = (float)o01[j];
      v0 += f0*wp[j].y;   v1 += f0*wp[j].x;
      v0 += f1*wp[4+j].y; v1 += f1*wp[4+j].x;
      float g0 = (float)o10[j], g1 = (float)o11[j];
      v2 += g0*wp[j].y;   v3 += g0*wp[j].x;
      v2 += g1*wp[4+j].y; v3 += g1*wp[4+j].x;
    }
    size_t oi = (((size_t)b*256 + co)*64 + (mb*16 + y))*64 + xq*4;
    float4 qv = *reinterpret_cast<const float4*>(qin + oi);
    float4 ov;
    ov.x = qv.x + gm*v0; ov.y = qv.y + gm*v1;
    ov.z = qv.z + gm*v2; ov.w = qv.w + gm*v3;
    *reinterpret_cast<float4*>(outp + oi) = ov;
  }
}

extern "C" void kernel_launch(void* const* d_in, const int* in_sizes, int n_in,
                              void* d_out, int out_size, void* d_ws, size_t ws_size,
                              hipStream_t stream) {
  const float* q  = (const float*)d_in[0];
  const float* k  = (const float*)d_in[1];
  const float* v  = (const float*)d_in[2];
  const float* wq = (const float*)d_in[3];
  const float* bq = (const float*)d_in[4];
  const float* wk = (const float*)d_in[5];
  const float* bk = (const float*)d_in[6];
  const float* wv = (const float*)d_in[7];
  const float* bv = (const float*)d_in[8];
  const float* wo = (const float*)d_in[9];
  const float* bo = (const float*)d_in[10];
  const float* gamma = (const float*)d_in[11];
  float* out = (float*)d_out;

  char* ws = (char*)d_ws;
  bf16* Pk    = (bf16*)(ws);              //  33,554,432 B
  bf16* Vt    = (bf16*)(ws + 33554432);   //  33,554,432 B
  bf16* Pattn = (bf16*)(ws + 67108864);   //   8,388,608 B

  proj_kv  <<<dim3(512, 8), 256, 0, stream>>>(k, v, wk, bk, wv, bv, Pk, Vt);
  attn_fused<<<dim3(512), 256, 0, stream>>>(q, wq, bq, Pk, Pattn);
  pv_deconv<<<dim3(1024), 256, 0, stream>>>(Pattn, Vt, q, wo, bo, gamma, out);
}

// Round 6
// 80.974 us; speedup vs baseline: 1.1618x; 1.0531x over previous
//
#include <hip/hip_runtime.h>
#include <hip/hip_bf16.h>

typedef __bf16 bf16;
typedef __bf16 bf16x4 __attribute__((ext_vector_type(4)));
typedef __bf16 bf16x8 __attribute__((ext_vector_type(8)));
typedef float f32x4 __attribute__((ext_vector_type(4)));

// async global->LDS, 16B per lane. LDS dest must be wave-uniform (base+lane*16 is HW).
__device__ __forceinline__ void gload16(const void* g, void* l) {
  __builtin_amdgcn_global_load_lds(
      (const __attribute__((address_space(1))) unsigned int*)g,
      (__attribute__((address_space(3))) unsigned int*)l, 16, 0, 0);
}

// Layouts (bf16):
//  Pk:    FRAG order [bh][kb16][fr(16)][ks(2)][lane(64)][8]
//         elem (bh,c,l): kb=l>>6, fr=c>>4, ks=(l&63)>>5, lane=((l&31)>>3)*16+(c&15), u=l&7
//  Vt:    [bh][kb4][row l(1024)][64]   (k-dim = c)  col XOR uses l&7   (LDS-swizzled)
//  Pattn: [bh][kb4][row c(256)][64]    (k-dim = d)  col XOR uses c&7   (LDS-swizzled)

// ---------------- Kernel A: k-projection (x<256) + v-projection (x>=256), one launch
__global__ __launch_bounds__(256) void proj_kv(
    const float* __restrict__ kin, const float* __restrict__ vin,
    const float* __restrict__ wk, const float* __restrict__ bk,
    const float* __restrict__ wv, const float* __restrict__ bv,
    bf16* __restrict__ Pk, bf16* __restrict__ Vt) {
  int b = blockIdx.y;
  int x = blockIdx.x;
  int t = threadIdx.x;
  __shared__ float ch[4224];   // k-path: 4096; v-path: 32*2*66 = 4224
  if (x < 256) {
    // ---- k projection, group g = x, output in MFMA-frag order
    int g = x;
    {
      const float4* src = reinterpret_cast<const float4*>(kin + ((size_t)b*256 + g)*4096);
      float4* dst4 = reinterpret_cast<float4*>(ch);
#pragma unroll
      for (int i = 0; i < 4; i++) dst4[t + i*256] = src[t + i*256];
    }
    int j = t >> 5, i = t & 31;
    float4 wvv = reinterpret_cast<const float4*>(wk)[g*8 + j];
    float bj = bk[g*8 + j];
    __syncthreads();
    int h = g >> 5;
    int c = (g & 31)*8 + j;
    int bh = b*8 + h;
    int fr = c >> 4, lr2 = c & 15;
#pragma unroll
    for (int p = 0; p < 4; p++) {
      int l0 = p*256 + i*8;
      int m = l0 >> 5, kb = l0 >> 6, kp0 = l0 & 63, n0 = l0 & 31;
      int ks = kp0 >> 5, lg2 = (kp0 >> 3) & 3;
      float rr0[16], rr1[16];
      const float4* R0 = reinterpret_cast<const float4*>(ch + (2*m)*64 + 2*n0);
      const float4* R1 = reinterpret_cast<const float4*>(ch + (2*m+1)*64 + 2*n0);
#pragma unroll
      for (int u = 0; u < 4; u++) {
        *reinterpret_cast<float4*>(rr0 + u*4) = R0[u];
        *reinterpret_cast<float4*>(rr1 + u*4) = R1[u];
      }
      bf16x8 o;
#pragma unroll
      for (int u = 0; u < 8; u++)
        o[u] = (bf16)(bj + wvv.x*rr0[2*u] + wvv.y*rr0[2*u+1] + wvv.z*rr1[2*u] + wvv.w*rr1[2*u+1]);
      size_t off = ((size_t)(bh*16 + kb))*16384 + (size_t)(((fr*2 + ks)*64) + lg2*16 + lr2)*8;
      *reinterpret_cast<bf16x8*>(Pk + off) = o;
    }
  } else {
    // ---- v projection into swizzled chunk-transposed Vt
    int r = x - 256;
    int m = r & 31, h = r >> 5;
    {
      int seg = t >> 2, part = t & 3;
      int gl = seg >> 1, ky = seg & 1;
      const float* src = vin + (((size_t)b*256 + h*32 + gl)*64 + (2*m + ky))*64;
      float* drow = ch + (gl*2 + ky)*66;
#pragma unroll
      for (int i = 0; i < 4; i++) {
        float4 v = reinterpret_cast<const float4*>(src)[part + i*4];
        int x0 = (part + i*4)*4;
        drow[x0]=v.x; drow[x0+1]=v.y; drow[x0+2]=v.z; drow[x0+3]=v.w;
      }
    }
    int cgrp = t & 31, lgr = t >> 5;
    int c0 = cgrp*8;
    float4 wv8[8]; float bb8[8];
#pragma unroll
    for (int u = 0; u < 8; u++) {
      wv8[u] = reinterpret_cast<const float4*>(wv)[h*256 + c0 + u];
      bb8[u] = bv[h*256 + c0 + u];
    }
    __syncthreads();
    const float* r0 = ch + (cgrp*2 + 0)*66;
    const float* r1 = ch + (cgrp*2 + 1)*66;
    int bh = b*8 + h;
    bf16* base = Vt + ((size_t)bh*4 + (c0 >> 6))*1024*64;
    int colx = (c0 & 63) ^ (lgr << 3);
#pragma unroll
    for (int p = 0; p < 4; p++) {
      int n = p*8 + lgr;
      int l = m*32 + n;
      float c00 = r0[2*n], c01 = r0[2*n+1], c10 = r1[2*n], c11 = r1[2*n+1];
      bf16x8 o;
#pragma unroll
      for (int u = 0; u < 8; u++)
        o[u] = (bf16)(bb8[u] + wv8[u].x*c00 + wv8[u].y*c01 + wv8[u].z*c10 + wv8[u].w*c11);
      *reinterpret_cast<bf16x8*>(base + (size_t)l*64 + colx) = o;
    }
  }
}

// ---------------- Kernel B: fused Q-proj + S = Q K^T + softmax -> Pattn.
// 512 blocks, 4 waves, 32 c-rows/block. K frags loaded DIRECTLY global->VGPR
// (frag-order Pk, no LDS for K). Q double-buffered in LDS, ONE raw barrier/chunk,
// no vmcnt drain at barriers (K prefetch stays in flight, T4-style).
__global__ __launch_bounds__(256, 2) void attn_fused(
    const float* __restrict__ qraw, const float* __restrict__ wq,
    const float* __restrict__ bq, const bf16* __restrict__ Pk,
    bf16* __restrict__ Pattn) {
  int raw = blockIdx.x;
  int loc = raw >> 3;
  int bh = (raw & 7)*8 + (loc >> 3);   // 8 c-strips of one bh share an XCD
  int tb = loc & 7;
  int c0 = tb*32;
  int b = bh >> 3, h = bh & 7;
  int t = threadIdx.x, wave = t >> 6, lane = t & 63, lg = lane >> 4, lr = lane & 15;
  int cl = lane & 7, cg = lane >> 3;   // c_local (=j), col-group
  __shared__ bf16 Qb[2][2048];    // double-buffered Q chunk (32 rows x 64)
  __shared__ bf16 Pst[8192];      // P staging for coalesced copy-out (16 KB)
  __shared__ float red_s[4][32];
  // ---- Q-conv setup: this wave's conv group g; lane computes 8 l's of row c=g*8+cl
  int g = h*32 + tb*4 + wave;
  const float* qch = qraw + ((size_t)b*256 + g)*4096;
  float4 wvq = reinterpret_cast<const float4*>(wq)[g*8 + cl];
  float bj = bq[g*8 + cl];
  int x0 = (cg & 3)*16;
  int yb = (cg >> 2)*2;
  bf16* qlw0 = &Qb[0][(wave*8 + cl)*64 + ((cg*8) ^ (cl << 3))];
  bf16* qlw1 = &Qb[1][(wave*8 + cl)*64 + ((cg*8) ^ (cl << 3))];
  // ---- K frag base (per lane): frag(ct,ni,ks) at +ct*32768 + ni*2048 + ks*1024
  const char* Kb0 = (const char*)Pk + (size_t)bh*524288 + wave*8192 + (size_t)lane*16;

  float4 qf0[4], qf1[4];
#define QLOAD(ct) { int y0 = (ct)*4 + yb; \
    const float4* R0 = reinterpret_cast<const float4*>(qch + y0*64 + x0); \
    const float4* R1 = reinterpret_cast<const float4*>(qch + (y0+1)*64 + x0); \
    qf0[0]=R0[0]; qf0[1]=R0[1]; qf0[2]=R0[2]; qf0[3]=R0[3]; \
    qf1[0]=R1[0]; qf1[1]=R1[1]; qf1[2]=R1[2]; qf1[3]=R1[3]; }
#define QWRITE(dst) { const float* f0 = (const float*)qf0; const float* f1 = (const float*)qf1; \
    bf16x8 o; \
    _Pragma("unroll") \
    for (int u = 0; u < 8; u++) \
      o[u] = (bf16)(bj + wvq.x*f0[2*u] + wvq.y*f0[2*u+1] + wvq.z*f1[2*u] + wvq.w*f1[2*u+1]); \
    *reinterpret_cast<bf16x8*>(dst) = o; }
#define LOADK(ct, dst) { const char* kp = Kb0 + (size_t)(ct)*32768; \
    _Pragma("unroll") \
    for (int ni = 0; ni < 4; ni++) { \
      (dst)[ni*2]   = *reinterpret_cast<const bf16x8*>(kp + ni*2048); \
      (dst)[ni*2+1] = *reinterpret_cast<const bf16x8*>(kp + ni*2048 + 1024); \
    } }

  bf16x8 kreg[2][8];
  f32x4 acc[2][4];
#pragma unroll
  for (int i = 0; i < 2; i++)
#pragma unroll
    for (int j = 0; j < 4; j++) { f32x4 z = {0.f,0.f,0.f,0.f}; acc[i][j] = z; }

  // prologue: chunk 0 (qf FIRST, then kreg: FIFO vmcnt -> qf wait leaves kreg in flight)
  QLOAD(0);
  LOADK(0, kreg[0]);
  QWRITE(qlw0);                         // Q[0] -> Qb[0]
#pragma unroll
  for (int ct = 0; ct < 16; ct++) {
    const int cur = ct & 1;
    if (ct < 15) { QLOAD(ct + 1); LOADK(ct + 1, kreg[cur ^ 1]); }
    asm volatile("s_waitcnt lgkmcnt(0)" ::: "memory");  // own Q write + Q reads drained
    __builtin_amdgcn_s_barrier();                       // Q[ct] visible to all waves
    __builtin_amdgcn_sched_barrier(0);                  // nothing crosses the barrier
    if (ct < 15) { if (cur) QWRITE(qlw0) else QWRITE(qlw1) }  // Q[ct+1] -> Qb[(ct+1)&1]
    const bf16* Qcur = Qb[cur];
#pragma unroll
    for (int ks = 0; ks < 2; ks++) {
      int colx = (ks*32 + lg*8) ^ ((lr & 7) << 3);
      bf16x8 a0 = *reinterpret_cast<const bf16x8*>(Qcur + lr*64 + colx);
      bf16x8 a1 = *reinterpret_cast<const bf16x8*>(Qcur + (16 + lr)*64 + colx);
#pragma unroll
      for (int ni = 0; ni < 4; ni++) {
        acc[0][ni] = __builtin_amdgcn_mfma_f32_16x16x32_bf16(a0, kreg[cur][ni*2+ks], acc[0][ni], 0, 0, 0);
        acc[1][ni] = __builtin_amdgcn_mfma_f32_16x16x32_bf16(a1, kreg[cur][ni*2+ks], acc[1][ni], 0, 0, 0);
      }
    }
  }
#undef QLOAD
#undef QWRITE
#undef LOADK
  // softmax over d (wave holds 64 d; combine 4 waves via red_s)
  const float scale = 0.03125f;
  float sums[2][4];
#pragma unroll
  for (int mi = 0; mi < 2; mi++)
#pragma unroll
    for (int r = 0; r < 4; r++) {
      float mx = fmaxf(fmaxf(acc[mi][0][r], acc[mi][1][r]), fmaxf(acc[mi][2][r], acc[mi][3][r]));
#pragma unroll
      for (int off = 1; off < 16; off <<= 1) mx = fmaxf(mx, __shfl_xor(mx, off, 64));
      red_s[wave][mi*16 + lg*4 + r] = mx;
    }
  __syncthreads();
#pragma unroll
  for (int mi = 0; mi < 2; mi++)
#pragma unroll
    for (int r = 0; r < 4; r++) {
      int clr = mi*16 + lg*4 + r;
      float mx = fmaxf(fmaxf(red_s[0][clr], red_s[1][clr]), fmaxf(red_s[2][clr], red_s[3][clr]));
      float s = 0.f;
#pragma unroll
      for (int ni = 0; ni < 4; ni++) {
        float p = __expf(scale*(acc[mi][ni][r] - mx));
        acc[mi][ni][r] = p; s += p;
      }
#pragma unroll
      for (int off = 1; off < 16; off <<= 1) s += __shfl_xor(s, off, 64);
      sums[mi][r] = s;
    }
  __syncthreads();
#pragma unroll
  for (int mi = 0; mi < 2; mi++)
#pragma unroll
    for (int r = 0; r < 4; r++) red_s[wave][mi*16 + lg*4 + r] = sums[mi][r];
  __syncthreads();
  // normalize + stage P strip into LDS in swizzled chunk layout
#pragma unroll
  for (int mi = 0; mi < 2; mi++)
#pragma unroll
    for (int r = 0; r < 4; r++) {
      int clr = mi*16 + lg*4 + r;
      float iv = 1.f/(red_s[0][clr] + red_s[1][clr] + red_s[2][clr] + red_s[3][clr]);
#pragma unroll
      for (int ni = 0; ni < 4; ni++) {
        int dl = ni*16 + lr;
        Pst[wave*2048 + clr*64 + (dl ^ ((clr & 7) << 3))] = (bf16)(acc[mi][ni][r]*iv);
      }
    }
  __syncthreads();
  // coalesced copy-out: 4 pieces of 4KB
  const uint4* ls = reinterpret_cast<const uint4*>(Pst);
#pragma unroll
  for (int i = 0; i < 4; i++) {
    uint4* gp = reinterpret_cast<uint4*>((char*)Pattn + (((size_t)bh*4 + i)*256 + c0)*128);
    gp[t] = ls[i*256 + t];
  }
}

// ---------------- Kernel C: O = Pattn * V (K=256), fused deconv + bias + residual
__global__ __launch_bounds__(256, 4) void pv_deconv(const bf16* __restrict__ Pattn,
    const bf16* __restrict__ Vt, const float* __restrict__ qin,
    const float* __restrict__ wo, const float* __restrict__ bo,
    const float* __restrict__ gamma, float* __restrict__ outp) {
  int raw = blockIdx.x;
  int idx = raw >> 3;
  int pair = (raw & 7)*32 + (idx >> 2);   // (mb,bh); 4 tb-blocks share V chunk + XCD
  int tb = idx & 3;
  int mb = pair & 3, bh = pair >> 2;
  int h = bh & 7, b = bh >> 3;
  int t = threadIdx.x, wave = t >> 6, lane = t & 63, lg = lane >> 4, lr = lane & 15;
  __shared__ __attribute__((aligned(16))) char smem[40960];
  bf16* Pl   = reinterpret_cast<bf16*>(smem);            // 8192 B
  bf16* Vl   = reinterpret_cast<bf16*>(smem + 8192);     // 32768 B
  bf16* OlT  = reinterpret_cast<bf16*>(smem);            // 256*66*2 = 33792 B (post-loop)
  float* wo_s = reinterpret_cast<float*>(smem + 36864);  // 1024 B (post-loop)
  float* bo_s = reinterpret_cast<float*>(smem + 37888);  // 32 B
  const char* Pbase = (const char*)Pattn + ((size_t)bh*4*256 + tb*64)*128;
  const char* Vbase = (const char*)Vt + ((size_t)bh*4*1024 + mb*256)*128;
  f32x4 acc[4][4];
#pragma unroll
  for (int i = 0; i < 4; i++)
#pragma unroll
    for (int j = 0; j < 4; j++) { f32x4 z = {0.f,0.f,0.f,0.f}; acc[i][j] = z; }
  for (int kb = 0; kb < 4; kb++) {
    __syncthreads();
    {
      const char* pc = Pbase + (size_t)kb*32768 + wave*2048 + lane*16;
      char* pl = (char*)Pl + wave*2048;
#pragma unroll
      for (int i = 0; i < 2; i++) gload16(pc + i*1024, pl + i*1024);
      const char* vc = Vbase + (size_t)kb*131072 + wave*8192 + lane*16;
      char* vl = (char*)Vl + wave*8192;
#pragma unroll
      for (int i = 0; i < 8; i++) gload16(vc + i*1024, vl + i*1024);
    }
    __syncthreads();
#pragma unroll
    for (int ks = 0; ks < 2; ks++) {
      int colx = (ks*32 + lg*8) ^ ((lr & 7) << 3);
      bf16x8 a[4];
#pragma unroll
      for (int mi = 0; mi < 4; mi++)
        a[mi] = *reinterpret_cast<const bf16x8*>(Pl + (mi*16 + lr)*64 + colx);
#pragma unroll
      for (int ni = 0; ni < 4; ni++) {
        bf16x8 bv2 = *reinterpret_cast<const bf16x8*>(Vl + (wave*64 + ni*16 + lr)*64 + colx);
#pragma unroll
        for (int mi = 0; mi < 4; mi++)
          acc[mi][ni] = __builtin_amdgcn_mfma_f32_16x16x32_bf16(a[mi], bv2, acc[mi][ni], 0, 0, 0);
      }
    }
  }
  __syncthreads();   // all MFMA LDS reads done before OlT/wo_s overwrite
#pragma unroll
  for (int mi = 0; mi < 4; mi++)
#pragma unroll
    for (int ni = 0; ni < 4; ni++) {
      int l = wave*64 + ni*16 + lr;
      int cb = mi*16 + lg*4;
      bf16x4 p;
      p[0] = (bf16)acc[mi][ni][0]; p[1] = (bf16)acc[mi][ni][1];
      p[2] = (bf16)acc[mi][ni][2]; p[3] = (bf16)acc[mi][ni][3];
      *reinterpret_cast<bf16x4*>(OlT + l*66 + cb) = p;
    }
  wo_s[t] = wo[((size_t)(h*32 + tb*8 + (t>>5)))*32 + (t & 31)];
  if (t < 8) bo_s[t] = bo[h*32 + tb*8 + t];
  __syncthreads();
  // epilogue: deconv 2x2 stride 2 + bias + residual; fully coalesced float4 I/O
  int xq = t & 15, b5 = (t >> 4) & 1, ct = t >> 5;
  float2 wp[8];
#pragma unroll
  for (int j = 0; j < 8; j++)
    wp[j] = *reinterpret_cast<const float2*>(wo_s + ct*32 + j*4 + (1 - b5)*2);
  float bias = bo_s[ct];
  float gm = gamma[0];
  int co = h*32 + tb*8 + ct;
#pragma unroll
  for (int it = 0; it < 8; it++) {
    int y = it*2 + b5;
    int ll0 = it*32 + xq*2;
    bf16x4 o00 = *reinterpret_cast<const bf16x4*>(OlT + ll0*66 + ct*8);
    bf16x4 o01 = *reinterpret_cast<const bf16x4*>(OlT + ll0*66 + ct*8 + 4);
    bf16x4 o10 = *reinterpret_cast<const bf16x4*>(OlT + (ll0+1)*66 + ct*8);
    bf16x4 o11 = *reinterpret_cast<const bf16x4*>(OlT + (ll0+1)*66 + ct*8 + 4);
    float v0 = bias, v1 = bias, v2 = bias, v3 = bias;
#pragma unroll
    for (int j = 0; j < 4; j++) {
      float f0 = (float)o00[j], f1 = (float)o01[j];
      v0 += f0*wp[j].y;   v1 += f0*wp[j].x;
      v0 += f1*wp[4+j].y; v1 += f1*wp[4+j].x;
      float g0 = (float)o10[j], g1 = (float)o11[j];
      v2 += g0*wp[j].y;   v3 += g0*wp[j].x;
      v2 += g1*wp[4+j].y; v3 += g1*wp[4+j].x;
    }
    size_t oi = (((size_t)b*256 + co)*64 + (mb*16 + y))*64 + xq*4;
    float4 qv = *reinterpret_cast<const float4*>(qin + oi);
    float4 ov;
    ov.x = qv.x + gm*v0; ov.y = qv.y + gm*v1;
    ov.z = qv.z + gm*v2; ov.w = qv.w + gm*v3;
    *reinterpret_cast<float4*>(outp + oi) = ov;
  }
}

extern "C" void kernel_launch(void* const* d_in, const int* in_sizes, int n_in,
                              void* d_out, int out_size, void* d_ws, size_t ws_size,
                              hipStream_t stream) {
  const float* q  = (const float*)d_in[0];
  const float* k  = (const float*)d_in[1];
  const float* v  = (const float*)d_in[2];
  const float* wq = (const float*)d_in[3];
  const float* bq = (const float*)d_in[4];
  const float* wk = (const float*)d_in[5];
  const float* bk = (const float*)d_in[6];
  const float* wv = (const float*)d_in[7];
  const float* bv = (const float*)d_in[8];
  const float* wo = (const float*)d_in[9];
  const float* bo = (const float*)d_in[10];
  const float* gamma = (const float*)d_in[11];
  float* out = (float*)d_out;

  char* ws = (char*)d_ws;
  bf16* Pk    = (bf16*)(ws);              //  33,554,432 B
  bf16* Vt    = (bf16*)(ws + 33554432);   //  33,554,432 B
  bf16* Pattn = (bf16*)(ws + 67108864);   //   8,388,608 B

  proj_kv  <<<dim3(512, 8), 256, 0, stream>>>(k, v, wk, bk, wv, bv, Pk, Vt);
  attn_fused<<<dim3(512), 256, 0, stream>>>(q, wq, bq, Pk, Pattn);
  pv_deconv<<<dim3(1024), 256, 0, stream>>>(Pattn, Vt, q, wo, bo, gamma, out);
}